// Round 2
// baseline (98.175 us; speedup 1.0000x reference)
//
#include <hip/hip_runtime.h>
#include <hip/hip_bf16.h>
#include <stdint.h>

// out = q5( q5(x) @fixedpoint q5(W) + b ), q5(a)=trunc(32a)/32
// Exact integer reformulation (verified absmax 0.0 in round 1):
//   A = trunc(x) (small ints, exact in bf16), B = trunc(32W) restricted to
//   {-1,0,1}; rare |iw|>=2 entries zeroed in B and patched exactly in the
//   GEMM epilogue from a per-tile entry list. out = trunc(Cint + 32b)/32.

#define M_DIM 1024
#define N_DIM 1024
#define K_DIM 2048
#define ESLOTS 16

typedef float f32x4 __attribute__((ext_vector_type(4)));
typedef __bf16 bf16x8 __attribute__((ext_vector_type(8)));

// ws layout: Aimg 4MB | Bimg 4MB | entcnt 2KB | ents 64KB
#define A_OFF    0u
#define B_OFF    (4u << 20)
#define ENTC_OFF (8u << 20)
#define ENT_OFF  ((8u << 20) + 4096u)

static __device__ __forceinline__ unsigned short f2bf(float f) {
    // exact for our small-integer values
    return (unsigned short)(__builtin_bit_cast(unsigned, f) >> 16);
}

static __device__ __forceinline__ void gload16(const void* g, void* l) {
    // global->LDS async, 16B/lane; LDS operand is the wave-uniform base
    __builtin_amdgcn_global_load_lds(
        (__attribute__((address_space(1))) void*)(void*)g,
        (__attribute__((address_space(3))) void*)l,
        16, 0, 0);
}

// Fused quantizer: blocks [0,1024) -> x->Aimg, blocks [1024,1536) -> W->Bimg.
// Images are tile-formatted and XOR-swizzled so the GEMM's linear
// global_load_lds + swizzled ds_read_b128 is bank-conflict-minimal.
__global__ __launch_bounds__(256) void quant_kernel(
    const float* __restrict__ x, const float* __restrict__ W,
    unsigned char* __restrict__ Aimg, unsigned char* __restrict__ Bimg,
    int* __restrict__ entcnt, int* __restrict__ ents) {
    __shared__ unsigned short lt[64][80];
    __shared__ int s_cnt;
    __shared__ int s_ent[ESLOTS][2];
    int blk = blockIdx.x;
    int t = threadIdx.x;
    if (blk < 1024) {
        int g = blk * 256 + t;
        int row = g >> 8;
        int k0 = (g & 255) << 3;
        const float* p = x + row * K_DIM + k0;
        float4 v0 = *(const float4*)p;
        float4 v1 = *(const float4*)(p + 4);
        uint4 o;
        o.x = (unsigned)f2bf(truncf(v0.x)) | ((unsigned)f2bf(truncf(v0.y)) << 16);
        o.y = (unsigned)f2bf(truncf(v0.z)) | ((unsigned)f2bf(truncf(v0.w)) << 16);
        o.z = (unsigned)f2bf(truncf(v1.x)) | ((unsigned)f2bf(truncf(v1.y)) << 16);
        o.w = (unsigned)f2bf(truncf(v1.z)) | ((unsigned)f2bf(truncf(v1.w)) << 16);
        int mt = row >> 6, r = row & 63, kt = k0 >> 6, kk = k0 & 63;
        unsigned off = (unsigned)(mt * 32 + kt) * 8192u + (unsigned)r * 128u
                     + (((unsigned)kk * 2u) ^ (((unsigned)(r & 7)) << 4));
        *(uint4*)(Aimg + off) = o;
    } else {
        int wb = blk - 1024;                // 0..511 = (kt, nt) tile
        int kt = wb >> 4, nt = wb & 15;
        if (t == 0) s_cnt = 0;
        __syncthreads();
#pragma unroll
        for (int i = 0; i < 16; ++i) {
            int e = t + i * 256;
            int kk = e >> 6, j = e & 63;
            float wv = W[(kt * 64 + kk) * N_DIM + nt * 64 + j];
            float iwf = truncf(wv * 32.0f);
            unsigned short bw;
            if (iwf > 1.0f || iwf < -1.0f) {
                bw = 0;
                int pos = atomicAdd(&s_cnt, 1);
                if (pos < ESLOTS) {
                    s_ent[pos][0] = ((kt * 64 + kk) << 16) | (nt * 64 + j);
                    s_ent[pos][1] = (int)iwf;
                }
            } else {
                bw = f2bf(iwf);
            }
            lt[j][kk] = bw;
        }
        __syncthreads();
        int j = t >> 2, seg = t & 3, k0 = seg * 16;
        unsigned short tmp[16];
#pragma unroll
        for (int q = 0; q < 16; ++q) tmp[q] = lt[j][k0 + q];
        uint4 c0, c1;
        c0.x = (unsigned)tmp[0]  | ((unsigned)tmp[1]  << 16);
        c0.y = (unsigned)tmp[2]  | ((unsigned)tmp[3]  << 16);
        c0.z = (unsigned)tmp[4]  | ((unsigned)tmp[5]  << 16);
        c0.w = (unsigned)tmp[6]  | ((unsigned)tmp[7]  << 16);
        c1.x = (unsigned)tmp[8]  | ((unsigned)tmp[9]  << 16);
        c1.y = (unsigned)tmp[10] | ((unsigned)tmp[11] << 16);
        c1.z = (unsigned)tmp[12] | ((unsigned)tmp[13] << 16);
        c1.w = (unsigned)tmp[14] | ((unsigned)tmp[15] << 16);
        unsigned base = (unsigned)wb * 8192u + (unsigned)j * 128u;
        unsigned sw = ((unsigned)(j & 7)) << 4;
        *(uint4*)(Bimg + base + (((unsigned)(2 * k0)) ^ sw)) = c0;
        *(uint4*)(Bimg + base + (((unsigned)(2 * k0 + 16)) ^ sw)) = c1;
        int c = s_cnt < ESLOTS ? s_cnt : ESLOTS;
        if (t == 0) entcnt[wb] = c;
        if (t < c) {
            ents[(wb * ESLOTS + t) * 2 + 0] = s_ent[t][0];
            ents[(wb * ESLOTS + t) * 2 + 1] = s_ent[t][1];
        }
    }
}

// 64x64-tile bf16 MFMA GEMM, 2-phase double-buffered pipeline (T3-min),
// fused correction-scan + bias + trunc epilogue with coalesced float4 stores.
__global__ __launch_bounds__(256) void gemm_kernel(
    const unsigned char* __restrict__ Aimg, const unsigned char* __restrict__ Bimg,
    const float* __restrict__ x, const float* __restrict__ bias,
    const int* __restrict__ entcnt, const int* __restrict__ ents,
    float* __restrict__ out) {
    __shared__ unsigned char smem[32768];   // [A0|A1|B0|B1], reused as Cs[64][68]
    int bm = blockIdx.x & 15, bn = blockIdx.x >> 4;
    int t = threadIdx.x, lane = t & 63, w = t >> 6;
    int wr = w >> 1, wc = w & 1;            // 2x2 waves of 32x32
    int lr = lane & 15, lg = lane >> 4;
    f32x4 acc[2][2] = {};

    const unsigned char* Abase = Aimg + (unsigned)bm * 262144u;   // 32 tiles
    const unsigned char* Bbase = Bimg + (unsigned)bn * 8192u;     // stride 16 tiles
    unsigned sog = (unsigned)(w * 2048 + lane * 16);              // global (per-lane)
    unsigned sol = (unsigned)(w * 2048);                          // LDS (uniform)

    auto stage = [&](int buf, int kt) {
        const unsigned char* ga = Abase + (unsigned)kt * 8192u + sog;
        const unsigned char* gb = Bbase + (unsigned)kt * 131072u + sog;
        unsigned char* la = smem + buf * 8192 + sol;
        unsigned char* lb = smem + 16384 + buf * 8192 + sol;
        gload16(ga,        la);
        gload16(ga + 1024, la + 1024);
        gload16(gb,        lb);
        gload16(gb + 1024, lb + 1024);
    };

    stage(0, 0);
    __syncthreads();
    int cur = 0;
    for (int kt = 0; kt < 32; ++kt) {
        if (kt < 31) stage(cur ^ 1, kt + 1);   // prefetch flies under compute
        const unsigned char* As = smem + cur * 8192;
        const unsigned char* Bs = smem + 16384 + cur * 8192;
#pragma unroll
        for (int kh = 0; kh < 2; ++kh) {
            int kb2 = (kh * 32 + lg * 8) * 2;
            bf16x8 aF[2], bF[2];
#pragma unroll
            for (int mi = 0; mi < 2; ++mi) {
                int r = wr * 32 + mi * 16 + lr;
                unsigned off = (unsigned)r * 128u
                             + (((unsigned)kb2) ^ (((unsigned)(r & 7)) << 4));
                aF[mi] = __builtin_bit_cast(bf16x8, *(const uint4*)(As + off));
            }
#pragma unroll
            for (int ni = 0; ni < 2; ++ni) {
                int c = wc * 32 + ni * 16 + lr;
                unsigned off = (unsigned)c * 128u
                             + (((unsigned)kb2) ^ (((unsigned)(c & 7)) << 4));
                bF[ni] = __builtin_bit_cast(bf16x8, *(const uint4*)(Bs + off));
            }
#pragma unroll
            for (int mi = 0; mi < 2; ++mi)
#pragma unroll
                for (int ni = 0; ni < 2; ++ni)
                    acc[mi][ni] = __builtin_amdgcn_mfma_f32_16x16x32_bf16(
                        aF[mi], bF[ni], acc[mi][ni], 0, 0, 0);
        }
        __syncthreads();   // drain: next tile landed; all waves done with cur
        cur ^= 1;
    }

    // exact patch for |iw|>=2 entries (normally zero iterations)
    for (int kt = 0; kt < 32; ++kt) {
        int wb = kt * 16 + bn;
        int c = entcnt[wb];
        for (int e = 0; e < c; ++e) {
            int pj = ents[(wb * ESLOTS + e) * 2 + 0];
            int iw = ents[(wb * ESLOTS + e) * 2 + 1];
            int k = pj >> 16, j = pj & 0xFFFF;
            int jl = j - bn * 64;
#pragma unroll
            for (int ni = 0; ni < 2; ++ni) {
                if (wc * 32 + ni * 16 + lr == jl) {
#pragma unroll
                    for (int mi = 0; mi < 2; ++mi)
#pragma unroll
                        for (int r = 0; r < 4; ++r) {
                            int row = bm * 64 + wr * 32 + mi * 16 + lg * 4 + r;
                            int ix = (int)truncf(x[row * K_DIM + k] * 32.0f);
                            acc[mi][ni][r] += (float)((ix * iw) / 32);
                        }
                }
            }
        }
    }

    // epilogue: LDS transpose (stride 68 floats = 17x16B, conflict-light,
    // 16B-aligned) -> coalesced float4 stores of trunc(C + 32b)/32
    __syncthreads();
    float* Cs = (float*)smem;
#pragma unroll
    for (int mi = 0; mi < 2; ++mi)
#pragma unroll
        for (int ni = 0; ni < 2; ++ni)
#pragma unroll
            for (int r = 0; r < 4; ++r) {
                int rl = wr * 32 + mi * 16 + lg * 4 + r;
                int cl = wc * 32 + ni * 16 + lr;
                Cs[rl * 68 + cl] = acc[mi][ni][r];
            }
    __syncthreads();
#pragma unroll
    for (int i = 0; i < 4; ++i) {
        int idx = t + i * 256;              // 1024 float4s per 64x64 tile
        int row = idx >> 4, c4 = idx & 15;
        float4 v = *(const float4*)&Cs[row * 68 + c4 * 4];
        int gc = bn * 64 + c4 * 4;
        float4 bb = *(const float4*)&bias[gc];
        float4 o;
        o.x = truncf(v.x + 32.0f * bb.x) * 0.03125f;
        o.y = truncf(v.y + 32.0f * bb.y) * 0.03125f;
        o.z = truncf(v.z + 32.0f * bb.z) * 0.03125f;
        o.w = truncf(v.w + 32.0f * bb.w) * 0.03125f;
        *(float4*)&out[(bm * 64 + row) * N_DIM + gc] = o;
    }
}

extern "C" void kernel_launch(void* const* d_in, const int* in_sizes, int n_in,
                              void* d_out, int out_size, void* d_ws, size_t ws_size,
                              hipStream_t stream) {
    const float* x = (const float*)d_in[0];
    const float* W = (const float*)d_in[1];
    const float* b = (const float*)d_in[2];
    float* out = (float*)d_out;
    unsigned char* ws = (unsigned char*)d_ws;
    unsigned char* Aimg = ws + A_OFF;
    unsigned char* Bimg = ws + B_OFF;
    int* entcnt = (int*)(ws + ENTC_OFF);
    int* ents   = (int*)(ws + ENT_OFF);

    quant_kernel<<<1536, 256, 0, stream>>>(x, W, Aimg, Bimg, entcnt, ents);
    gemm_kernel<<<256, 256, 0, stream>>>(Aimg, Bimg, x, b, entcnt, ents, out);
}

// Round 3
// 88.733 us; speedup vs baseline: 1.1064x; 1.1064x over previous
//
#include <hip/hip_runtime.h>
#include <hip/hip_bf16.h>
#include <stdint.h>

// out = q5( q5(x) @fixedpoint q5(W) + b ), q5(a)=trunc(32a)/32
// Exact integer reformulation (absmax 0.0 verified rounds 1-2):
//   A = trunc(x) (ints in [-6,6]), B = trunc(32W) restricted to {-1,0,1};
//   rare |iw|>=2 entries zeroed in B, patched exactly in the GEMM epilogue.
//   out = trunc(Cint + 32b)/32.  This round: i8 images + mfma_i32_16x16x64_i8
//   (2x bf16 rate, half the bytes everywhere); 8-wave GEMM with K-split.

#define M_DIM 1024
#define N_DIM 1024
#define K_DIM 2048
#define ESLOTS 16

typedef int i32x4 __attribute__((ext_vector_type(4)));

// ws: Aimg 2MB | Bimg 2MB | entcnt 1KB | ents 32KB
#define A_OFF    0u
#define B_OFF    (2u << 20)
#define ENTC_OFF (4u << 20)
#define ENT_OFF  ((4u << 20) + 4096u)

static __device__ __forceinline__ void gload16(const void* g, void* l) {
    // global->LDS async 16B/lane; global addr per-lane, LDS base wave-uniform
    __builtin_amdgcn_global_load_lds(
        (__attribute__((address_space(1))) void*)(void*)g,
        (__attribute__((address_space(3))) void*)l,
        16, 0, 0);
}

static __device__ __forceinline__ unsigned pk4(float a, float b, float c, float d) {
    return ((unsigned)((int)a & 255)) | ((unsigned)((int)b & 255) << 8) |
           ((unsigned)((int)c & 255) << 16) | ((unsigned)((int)d & 255) << 24);
}

// Fused quantizer. blocks [0,512): x -> Aimg (i8, tiled [mt16][kt16][64r][128B],
// 16B-unit XOR swizzle). blocks [512,768): W -> Bimg ([kt16][nt16][64c][128B])
// transposed per tile, + |iw|>=2 entry lists.
__global__ __launch_bounds__(256) void quant_kernel(
    const float* __restrict__ x, const float* __restrict__ W,
    unsigned char* __restrict__ Aimg, unsigned char* __restrict__ Bimg,
    int* __restrict__ entcnt, int* __restrict__ ents) {
    __shared__ signed char lt[64][144];
    __shared__ int s_cnt;
    __shared__ int s_ent[ESLOTS][2];
    int blk = blockIdx.x, t = threadIdx.x;
    if (blk < 512) {
        int g = blk * 256 + t;          // 131072 threads x 16 floats
        int row = g >> 7;
        int k0 = (g & 127) << 4;
        const float* p = x + row * K_DIM + k0;
        float4 v0 = *(const float4*)p;
        float4 v1 = *(const float4*)(p + 4);
        float4 v2 = *(const float4*)(p + 8);
        float4 v3 = *(const float4*)(p + 12);
        uint4 o;
        o.x = pk4(truncf(v0.x), truncf(v0.y), truncf(v0.z), truncf(v0.w));
        o.y = pk4(truncf(v1.x), truncf(v1.y), truncf(v1.z), truncf(v1.w));
        o.z = pk4(truncf(v2.x), truncf(v2.y), truncf(v2.z), truncf(v2.w));
        o.w = pk4(truncf(v3.x), truncf(v3.y), truncf(v3.z), truncf(v3.w));
        int mt = row >> 6, r = row & 63, kt = k0 >> 7, kb = k0 & 127;
        unsigned off = (unsigned)(mt * 16 + kt) * 8192u + (unsigned)r * 128u
                     + (((unsigned)kb) ^ (((unsigned)(r & 7)) << 4));
        *(uint4*)(Aimg + off) = o;
    } else {
        int wb = blk - 512;             // (kt, nt): 128-k x 64-n W tile
        int kt = wb >> 4, nt = wb & 15;
        if (t == 0) s_cnt = 0;
        __syncthreads();
#pragma unroll
        for (int i = 0; i < 32; ++i) {
            int e = t + i * 256;
            int kk = e >> 6, j = e & 63;
            float wv = W[(kt * 128 + kk) * N_DIM + nt * 64 + j];
            float iwf = truncf(wv * 32.0f);
            signed char bw;
            if (iwf > 1.0f || iwf < -1.0f) {
                bw = 0;
                int pos = atomicAdd(&s_cnt, 1);
                if (pos < ESLOTS) {
                    s_ent[pos][0] = ((kt * 128 + kk) << 16) | (nt * 64 + j);
                    s_ent[pos][1] = (int)iwf;
                }
            } else {
                bw = (signed char)(int)iwf;
            }
            lt[j][kk] = bw;
        }
        __syncthreads();
#pragma unroll
        for (int i = 0; i < 2; ++i) {
            int v = t * 2 + i;          // 512 16B units
            int col = v >> 3, uu = v & 7;
            uint4 c = *(const uint4*)&lt[col][uu * 16];
            unsigned off = (unsigned)wb * 8192u + (unsigned)col * 128u
                         + (((unsigned)(uu * 16)) ^ (((unsigned)(col & 7)) << 4));
            *(uint4*)(Bimg + off) = c;
        }
        int c = s_cnt < ESLOTS ? s_cnt : ESLOTS;
        if (t == 0) entcnt[wb] = c;
        if (t < c) {
            ents[(wb * ESLOTS + t) * 2 + 0] = s_ent[t][0];
            ents[(wb * ESLOTS + t) * 2 + 1] = s_ent[t][1];
        }
    }
}

// 64x64-tile i8 MFMA GEMM, 8 waves: quad q handles K-half q (8 tiles of K=128),
// double-buffered global_load_lds staging, cross-quad LDS reduce, fused
// patch + bias + trunc epilogue with coalesced float4 stores.
__global__ __launch_bounds__(512) void gemm_kernel(
    const unsigned char* __restrict__ Aimg, const unsigned char* __restrict__ Bimg,
    const float* __restrict__ x, const float* __restrict__ bias,
    const int* __restrict__ entcnt, const int* __restrict__ ents,
    float* __restrict__ out) {
    __shared__ unsigned char smem[65536];  // 2 quads x 2 bufs x (8KB A + 8KB B)
    int bm = blockIdx.x & 15, bn = blockIdx.x >> 4;
    int t = threadIdx.x, lane = t & 63, w = t >> 6;
    int q = w >> 2, wq = w & 3;
    int wr = wq >> 1, wc = wq & 1;          // 2x2 waves of 32x32 per quad
    int lr = lane & 15, lg = lane >> 4;
    i32x4 acc[2][2] = {};

    const unsigned char* Abase = Aimg + (unsigned)bm * 131072u;
    const unsigned char* Bbase = Bimg + (unsigned)bn * 8192u;
    unsigned char* qmem = smem + q * 32768;
    int ktbase = q * 8;

    auto stage = [&](int buf, int it) {
        int kt = ktbase + it;
        const unsigned char* ga = Abase + (unsigned)kt * 8192u + (unsigned)(wq * 2048 + lane * 16);
        const unsigned char* gb = Bbase + (unsigned)kt * 131072u + (unsigned)(wq * 2048 + lane * 16);
        unsigned char* la = qmem + buf * 16384 + wq * 2048;
        unsigned char* lb = la + 8192;
        gload16(ga,        la);
        gload16(ga + 1024, la + 1024);
        gload16(gb,        lb);
        gload16(gb + 1024, lb + 1024);
    };

    stage(0, 0);
    __syncthreads();
    int cur = 0;
    for (int it = 0; it < 8; ++it) {
        if (it < 7) stage(cur ^ 1, it + 1);
        const unsigned char* As = qmem + cur * 16384;
        const unsigned char* Bs = As + 8192;
#pragma unroll
        for (int kh = 0; kh < 2; ++kh) {
            int kb = kh * 64 + lg * 16;
            i32x4 aF[2], bF[2];
#pragma unroll
            for (int mi = 0; mi < 2; ++mi) {
                int r = wr * 32 + mi * 16 + lr;
                unsigned off = (unsigned)r * 128u
                             + (((unsigned)kb) ^ (((unsigned)(r & 7)) << 4));
                aF[mi] = *(const i32x4*)(As + off);
            }
#pragma unroll
            for (int ni = 0; ni < 2; ++ni) {
                int c = wc * 32 + ni * 16 + lr;
                unsigned off = (unsigned)c * 128u
                             + (((unsigned)kb) ^ (((unsigned)(c & 7)) << 4));
                bF[ni] = *(const i32x4*)(Bs + off);
            }
#pragma unroll
            for (int mi = 0; mi < 2; ++mi)
#pragma unroll
                for (int ni = 0; ni < 2; ++ni)
                    acc[mi][ni] = __builtin_amdgcn_mfma_i32_16x16x64_i8(
                        aF[mi], bF[ni], acc[mi][ni], 0, 0, 0);
        }
        __syncthreads();
        cur ^= 1;
    }

    // cross-quad reduce: quad 1 -> LDS, quad 0 accumulates
    int* red = (int*)smem;
    if (q == 1) {
        int bix = (t - 256) * 16;
#pragma unroll
        for (int mi = 0; mi < 2; ++mi)
#pragma unroll
            for (int ni = 0; ni < 2; ++ni)
#pragma unroll
                for (int r = 0; r < 4; ++r)
                    red[bix + mi * 8 + ni * 4 + r] = acc[mi][ni][r];
    }
    __syncthreads();
    if (q == 0) {
        int bix = t * 16;
#pragma unroll
        for (int mi = 0; mi < 2; ++mi)
#pragma unroll
            for (int ni = 0; ni < 2; ++ni)
#pragma unroll
                for (int r = 0; r < 4; ++r)
                    acc[mi][ni][r] += red[bix + mi * 8 + ni * 4 + r];
        // exact patch for |iw|>=2 (normally zero iterations)
        for (int kt = 0; kt < 16; ++kt) {
            int wb = kt * 16 + bn;
            int c = entcnt[wb];
            for (int e = 0; e < c; ++e) {
                int pj = ents[(wb * ESLOTS + e) * 2 + 0];
                int iw = ents[(wb * ESLOTS + e) * 2 + 1];
                int k = pj >> 16, jl = (pj & 0xFFFF) - bn * 64;
#pragma unroll
                for (int ni = 0; ni < 2; ++ni) {
                    if (wc * 32 + ni * 16 + lr == jl) {
#pragma unroll
                        for (int mi = 0; mi < 2; ++mi)
#pragma unroll
                            for (int r = 0; r < 4; ++r) {
                                int row = bm * 64 + wr * 32 + mi * 16 + lg * 4 + r;
                                int ix = (int)truncf(x[row * K_DIM + k] * 32.0f);
                                acc[mi][ni][r] += (ix * iw) / 32;  // C div = trunc
                            }
                    }
                }
            }
        }
    }
    __syncthreads();

    // epilogue via stride-68 LDS transpose -> coalesced float4 stores
    float* Cs = (float*)smem;
    if (q == 0) {
#pragma unroll
        for (int mi = 0; mi < 2; ++mi)
#pragma unroll
            for (int ni = 0; ni < 2; ++ni)
#pragma unroll
                for (int r = 0; r < 4; ++r) {
                    int rl = wr * 32 + mi * 16 + lg * 4 + r;
                    int cl = wc * 32 + ni * 16 + lr;
                    Cs[rl * 68 + cl] = (float)acc[mi][ni][r];
                }
    }
    __syncthreads();
#pragma unroll
    for (int i = 0; i < 2; ++i) {
        int idx = t + i * 512;              // 1024 float4s per 64x64 tile
        int row = idx >> 4, c4 = idx & 15;
        float4 v = *(const float4*)&Cs[row * 68 + c4 * 4];
        int gc = bn * 64 + c4 * 4;
        float4 bb = *(const float4*)&bias[gc];
        float4 o;
        o.x = truncf(v.x + 32.0f * bb.x) * 0.03125f;
        o.y = truncf(v.y + 32.0f * bb.y) * 0.03125f;
        o.z = truncf(v.z + 32.0f * bb.z) * 0.03125f;
        o.w = truncf(v.w + 32.0f * bb.w) * 0.03125f;
        *(float4*)&out[(bm * 64 + row) * N_DIM + gc] = o;
    }
}

extern "C" void kernel_launch(void* const* d_in, const int* in_sizes, int n_in,
                              void* d_out, int out_size, void* d_ws, size_t ws_size,
                              hipStream_t stream) {
    const float* x = (const float*)d_in[0];
    const float* W = (const float*)d_in[1];
    const float* b = (const float*)d_in[2];
    float* out = (float*)d_out;
    unsigned char* ws = (unsigned char*)d_ws;
    unsigned char* Aimg = ws + A_OFF;
    unsigned char* Bimg = ws + B_OFF;
    int* entcnt = (int*)(ws + ENTC_OFF);
    int* ents   = (int*)(ws + ENT_OFF);

    quant_kernel<<<768, 256, 0, stream>>>(x, W, Aimg, Bimg, entcnt, ents);
    gemm_kernel<<<256, 512, 0, stream>>>(Aimg, Bimg, x, b, entcnt, ents, out);
}